// Round 2
// 438.623 us; speedup vs baseline: 1.0519x; 1.0519x over previous
//
#include <hip/hip_runtime.h>

#define BB 4
#define NN 50000
#define DD 256
#define EE 800000
#define TAU_MIN_F 0.001f
#define MAX_CORR_F 0.15f

#define CAP 80                           // bucket capacity; P(deg>80) ~ 5e-7 for Binom(1.6M, 1/50K), mean 32
#define NPART 8                          // one partition per XCD
#define PNODES (NN / NPART)              // 6250 nodes -> bucket span 6250*80*8B = 4 MB, fits L2
#define PS_CE 2048                       // edges per chunk
#define PS_NCHUNK ((EE + PS_CE - 1) / PS_CE)  // 391

#define XPB 2048                         // xpred blocks inside fused stage-1 (multiple of 8 keeps XCD pinning)
#define S1_GRID (XPB + NPART * PS_NCHUNK)    // 2048 + 3128 = 5176
#define NWAVE (XPB * 4)                  // 8192 waves working the xpred items

// ---------------- Fused stage 1.
// Blocks [0, XPB): x = keypoints + tau * (hand_tokens @ head_w + head_b).
//   One wave per item i = node*4 + b. Lane l loads float4 at d=4*l (full 1KB row).
//   TWO items per loop iteration with the six shfl-reduce chains interleaved so the
//   DS-pipe latency of one chain hides under the other.
// Blocks [XPB, S1_GRID): bucketed adjacency build (independent of xpred -> overlap).
//   pb = blockIdx.x - XPB; partition = pb&7 (XPB%8==0 keeps partition p on XCD p so
//   the 4MB bucket write window stays L2-resident); chunk = pb>>3.
//   Neighbor index is stored PRE-SHIFTED (<<2) so gather indexes xin directly.
__global__ __launch_bounds__(256) void stage1_kernel(
    const float* __restrict__ kp, const float* __restrict__ ts,
    const float* __restrict__ ht, const float* __restrict__ hw,
    const float* __restrict__ hb, float4* __restrict__ x,
    const int* __restrict__ ei, const float* __restrict__ L0,
    int* __restrict__ counts, int2* __restrict__ adj)
{
    if ((int)blockIdx.x >= XPB) {
        const int pb    = (int)blockIdx.x - XPB;
        const int part  = pb & 7;
        const int chunk = pb >> 3;
        const int lo   = part * PNODES;
        const int hi   = lo + PNODES;
        const int base = chunk * PS_CE;
        const int eEnd = min(base + PS_CE, EE);
        for (int e = base + (int)threadIdx.x; e < eEnd; e += 256) {
            const int s = ei[e];
            const int d = ei[EE + e];
            const int r = __float_as_int(L0[e]);
            if (s >= lo && s < hi) {
                const int p = atomicAdd(&counts[s], 1);
                if (p < CAP) adj[s * CAP + p] = make_int2(d << 2, r);
            }
            if (d >= lo && d < hi) {
                const int p = atomicAdd(&counts[d], 1);
                if (p < CAP) adj[d * CAP + p] = make_int2(s << 2, r);
            }
        }
        return;
    }

    const int lane = threadIdx.x & 63;
    const int wave = ((int)blockIdx.x * 256 + (int)threadIdx.x) >> 6;
    const int d0   = lane * 4;

    float W[4][3];
#pragma unroll
    for (int j = 0; j < 4; ++j)
#pragma unroll
        for (int k = 0; k < 3; ++k)
            W[j][k] = hw[(d0 + j) * 3 + k];
    const float b0 = hb[0], b1 = hb[1], b2 = hb[2];

    int i = wave;
    for (; i + NWAVE < BB * NN; i += 2 * NWAVE) {
        const int iA = i, iB = i + NWAVE;
        const int rowA = (iA & 3) * NN + (iA >> 2);
        const int rowB = (iB & 3) * NN + (iB >> 2);
        const float4 hA = *(const float4*)(ht + (size_t)rowA * DD + d0);
        const float4 hB = *(const float4*)(ht + (size_t)rowB * DD + d0);
        float aA0 = hA.x * W[0][0] + hA.y * W[1][0] + hA.z * W[2][0] + hA.w * W[3][0];
        float aA1 = hA.x * W[0][1] + hA.y * W[1][1] + hA.z * W[2][1] + hA.w * W[3][1];
        float aA2 = hA.x * W[0][2] + hA.y * W[1][2] + hA.z * W[2][2] + hA.w * W[3][2];
        float aB0 = hB.x * W[0][0] + hB.y * W[1][0] + hB.z * W[2][0] + hB.w * W[3][0];
        float aB1 = hB.x * W[0][1] + hB.y * W[1][1] + hB.z * W[2][1] + hB.w * W[3][1];
        float aB2 = hB.x * W[0][2] + hB.y * W[1][2] + hB.z * W[2][2] + hB.w * W[3][2];
#pragma unroll
        for (int off = 32; off > 0; off >>= 1) {
            aA0 += __shfl_down(aA0, off);
            aB0 += __shfl_down(aB0, off);
            aA1 += __shfl_down(aA1, off);
            aB1 += __shfl_down(aB1, off);
            aA2 += __shfl_down(aA2, off);
            aB2 += __shfl_down(aB2, off);
        }
        if (lane == 0) {
            {
                const int bA = iA & 3;
                const float tau = fmaxf(1.0f - ts[bA], TAU_MIN_F);
                float4 v;
                v.x = kp[rowA * 3 + 0] + tau * (aA0 + b0);
                v.y = kp[rowA * 3 + 1] + tau * (aA1 + b1);
                v.z = kp[rowA * 3 + 2] + tau * (aA2 + b2);
                v.w = 0.0f;
                x[iA] = v;
            }
            {
                const int bB = iB & 3;
                const float tau = fmaxf(1.0f - ts[bB], TAU_MIN_F);
                float4 v;
                v.x = kp[rowB * 3 + 0] + tau * (aB0 + b0);
                v.y = kp[rowB * 3 + 1] + tau * (aB1 + b1);
                v.z = kp[rowB * 3 + 2] + tau * (aB2 + b2);
                v.w = 0.0f;
                x[iB] = v;
            }
        }
    }
    if (i < BB * NN) {
        const int row = (i & 3) * NN + (i >> 2);
        const float4 h = *(const float4*)(ht + (size_t)row * DD + d0);
        float a0 = h.x * W[0][0] + h.y * W[1][0] + h.z * W[2][0] + h.w * W[3][0];
        float a1 = h.x * W[0][1] + h.y * W[1][1] + h.z * W[2][1] + h.w * W[3][1];
        float a2 = h.x * W[0][2] + h.y * W[1][2] + h.z * W[2][2] + h.w * W[3][2];
#pragma unroll
        for (int off = 32; off > 0; off >>= 1) {
            a0 += __shfl_down(a0, off);
            a1 += __shfl_down(a1, off);
            a2 += __shfl_down(a2, off);
        }
        if (lane == 0) {
            const int b = i & 3;
            const float tau = fmaxf(1.0f - ts[b], TAU_MIN_F);
            float4 v;
            v.x = kp[row * 3 + 0] + tau * (a0 + b0);
            v.y = kp[row * 3 + 1] + tau * (a1 + b1);
            v.z = kp[row * 3 + 2] + tau * (a2 + b2);
            v.w = 0.0f;
            x[i] = v;
        }
    }
}

// ---------------- One Jacobi XPBD sweep, gather form, 32 threads per node.
// tid -> b = tid&3 (batch), sub = (tid>>2)&7 (bucket stripe), node = tid>>5.
// 8 stripes x ~4 entries each (avg deg 32), 2-way unrolled -> the whole per-thread
// dependent adj->xin chain is ~2 iterations deep with 4 loads in flight, and wave
// count doubles to 25K (vs 12.5K) for latency hiding. Reduce via shfl_xor(4/8/16).
__global__ __launch_bounds__(256) void gather_kernel(
    const float4* __restrict__ xin, float4* __restrict__ xout,
    const int* __restrict__ counts, const int2* __restrict__ adj,
    const float* __restrict__ kp, const float* __restrict__ ts,
    float* __restrict__ out, int final_iter)
{
    const int tid  = blockIdx.x * 256 + threadIdx.x;   // grid is exactly 32*NN
    const int b    = tid & 3;
    const int sub  = (tid >> 2) & 7;
    const int node = tid >> 5;

    const float4 xc = xin[(node << 2) + b];
    float a0 = 0.0f, a1 = 0.0f, a2 = 0.0f;            // correction only

    const int beg = node * CAP;
    const int end = beg + min(counts[node], CAP);

    int k = beg + sub;
    for (; k + 8 < end; k += 16) {
        const int2 e0 = adj[k];
        const int2 e1 = adj[k + 8];
        const float4 n0 = xin[e0.x + b];              // e.x pre-shifted (<<2) at build
        const float4 n1 = xin[e1.x + b];
        {
            const float dx = xc.x - n0.x, dy = xc.y - n0.y, dz = xc.z - n0.z;
            const float dist = sqrtf(dx * dx + dy * dy + dz * dz);
            const float s = (__int_as_float(e0.y) - dist) * 0.5f / (dist + 1e-9f);
            a0 += fminf(fmaxf(s * dx, -MAX_CORR_F), MAX_CORR_F);
            a1 += fminf(fmaxf(s * dy, -MAX_CORR_F), MAX_CORR_F);
            a2 += fminf(fmaxf(s * dz, -MAX_CORR_F), MAX_CORR_F);
        }
        {
            const float dx = xc.x - n1.x, dy = xc.y - n1.y, dz = xc.z - n1.z;
            const float dist = sqrtf(dx * dx + dy * dy + dz * dz);
            const float s = (__int_as_float(e1.y) - dist) * 0.5f / (dist + 1e-9f);
            a0 += fminf(fmaxf(s * dx, -MAX_CORR_F), MAX_CORR_F);
            a1 += fminf(fmaxf(s * dy, -MAX_CORR_F), MAX_CORR_F);
            a2 += fminf(fmaxf(s * dz, -MAX_CORR_F), MAX_CORR_F);
        }
    }
    if (k < end) {
        const int2 e0 = adj[k];
        const float4 n0 = xin[e0.x + b];
        const float dx = xc.x - n0.x, dy = xc.y - n0.y, dz = xc.z - n0.z;
        const float dist = sqrtf(dx * dx + dy * dy + dz * dz);
        const float s = (__int_as_float(e0.y) - dist) * 0.5f / (dist + 1e-9f);
        a0 += fminf(fmaxf(s * dx, -MAX_CORR_F), MAX_CORR_F);
        a1 += fminf(fmaxf(s * dy, -MAX_CORR_F), MAX_CORR_F);
        a2 += fminf(fmaxf(s * dz, -MAX_CORR_F), MAX_CORR_F);
    }

    // reduce the 8 sub-stripes (lanes differing in bits 2-4)
    a0 += __shfl_xor(a0, 4);  a0 += __shfl_xor(a0, 8);  a0 += __shfl_xor(a0, 16);
    a1 += __shfl_xor(a1, 4);  a1 += __shfl_xor(a1, 8);  a1 += __shfl_xor(a1, 16);
    a2 += __shfl_xor(a2, 4);  a2 += __shfl_xor(a2, 8);  a2 += __shfl_xor(a2, 16);

    if (sub == 0) {
        if (!final_iter) {
            float4 v; v.x = xc.x + a0; v.y = xc.y + a1; v.z = xc.z + a2; v.w = 0.0f;
            xout[(node << 2) + b] = v;
        } else {
            const int row = b * NN + node;            // out is (b, n, 3)
            const float tau = fmaxf(1.0f - ts[b], TAU_MIN_F);
            const float it  = 1.0f / tau;
            out[row * 3 + 0] = (xc.x + a0 - kp[row * 3 + 0]) * it;
            out[row * 3 + 1] = (xc.y + a1 - kp[row * 3 + 1]) * it;
            out[row * 3 + 2] = (xc.z + a2 - kp[row * 3 + 2]) * it;
        }
    }
}

extern "C" void kernel_launch(void* const* d_in, const int* in_sizes, int n_in,
                              void* d_out, int out_size, void* d_ws, size_t ws_size,
                              hipStream_t stream)
{
    const float* kp = (const float*)d_in[0];   // (B,N,3)
    const float* ts = (const float*)d_in[1];   // (B,)
    const float* ht = (const float*)d_in[2];   // (B,N,D)
    const float* hw = (const float*)d_in[3];   // (D,3)
    const float* hb = (const float*)d_in[4];   // (3,)
    const int*   ei = (const int*)d_in[5];     // (2,E)
    const float* L0 = (const float*)d_in[6];   // (E,)
    float* out = (float*)d_out;

    // Workspace layout
    char* w = (char*)d_ws;
    int2*   adj    = (int2*)w;                 w += (size_t)NN * CAP * sizeof(int2);     // 32 MB
    float4* xA     = (float4*)w;               w += (size_t)BB * NN * sizeof(float4);    // 3.2 MB
    float4* xB     = (float4*)w;               w += (size_t)BB * NN * sizeof(float4);    // 3.2 MB
    int*    counts = (int*)w;

    hipMemsetAsync(counts, 0, (size_t)NN * sizeof(int), stream);

    // Fused stage 1: x_pred (HBM-bound, 205 MB) overlapped with bucket build
    stage1_kernel<<<S1_GRID, 256, 0, stream>>>(kp, ts, ht, hw, hb, xA,
                                               ei, L0, counts, adj);

    // 4 Jacobi sweeps, ping-pong xA <-> xB, last fuses v_eff
    const int gatherBlocks = (32 * NN) / 256;          // 6250, exact
    gather_kernel<<<gatherBlocks, 256, 0, stream>>>(xA, xB, counts, adj, kp, ts, out, 0);
    gather_kernel<<<gatherBlocks, 256, 0, stream>>>(xB, xA, counts, adj, kp, ts, out, 0);
    gather_kernel<<<gatherBlocks, 256, 0, stream>>>(xA, xB, counts, adj, kp, ts, out, 0);
    gather_kernel<<<gatherBlocks, 256, 0, stream>>>(xB, xA, counts, adj, kp, ts, out, 1);
}